// Round 6
// baseline (79.896 us; speedup 1.0000x reference)
//
#include <hip/hip_runtime.h>

// DecisionTreePolicy — complete binary tree, depth 15 (32767 nodes).
// Internal 0..16382 (children 2i+1/2i+2), leaves 16383..32766 -> exactly 14
// steps from root; out[b] = leaf_logits[leaf(b)].
//
// R1/R2: scattered obs gathers -> 470 MB HBM, 84us. R4: obs streamed via LDS,
// tree in LDS -> 68.5us. R5: 16 waves redundant traversal -> LDS-pipe bound,
// 78us (inst count scales with waves!). R6: BLOCK=256, 32KB double-buffered
// tiles via global_load_lds DMA (issue-early/drain-late), child-prefetch
// traversal (children's thr/feat read in parallel with obs lookup -> one LDS
// round-trip per step), epilogue software-pipelined one tile behind.

#define N_INTERN  16383
#define N_FEAT    256
#define N_ACT     64
#define BATCH     262144
#define BLOCK     256
#define GRID      256
#define ROWS_PB   (BATCH / GRID)          // 1024 rows per block
#define TILE_ROWS 32
#define TILES     (ROWS_PB / TILE_ROWS)   // 32
#define DEPTH     14
#define CHUNKS    32                      // 1KB chunks per 32KB tile
#define WAVES     (BLOCK / 64)            // 4
#define CH_PER_W  (CHUNKS / WAVES)        // 8 DMA issues per wave per tile

typedef float f32x4 __attribute__((ext_vector_type(4)));
typedef __attribute__((address_space(3))) void        lds_void_t;
typedef const __attribute__((address_space(1))) void  glob_cvoid_t;

__device__ __forceinline__ void gload16(const void* g, void* l) {
    // async global->LDS DMA; LDS dest = wave-uniform base + lane*16 (HW rule)
    __builtin_amdgcn_global_load_lds((glob_cvoid_t*)g, (lds_void_t*)l, 16, 0, 0);
}

__global__ __launch_bounds__(BLOCK, 1) void tree_policy_kernel(
    const float* __restrict__ obs,          // [BATCH][N_FEAT]
    const int*   __restrict__ features,     // [N_NODES]
    const float* __restrict__ thresholds,   // [N_NODES]
    const float* __restrict__ leaf_logits,  // [N_NODES][N_ACT]
    float*       __restrict__ out)          // [BATCH][N_ACT]
{
    __shared__ float         sthr [N_INTERN];               // 64 KB
    __shared__ unsigned char sfeat[N_INTERN];               // 16 KB
    __shared__ __align__(16) float buf[2][TILE_ROWS * N_FEAT];  // 2 x 32 KB

    const int tid  = threadIdx.x;
    const int lane = tid & 63;
    const int wave = tid >> 6;
    const long rowBase = (long)blockIdx.x * ROWS_PB;

    // ---- tree -> LDS (one-time) ----
    for (int i = tid; i < N_INTERN; i += BLOCK) {
        sthr[i]  = thresholds[i];
        sfeat[i] = (unsigned char)features[i];
    }

    // ---- DMA tile 0 ----
    {
        const float* gbase = obs + rowBase * N_FEAT;
#pragma unroll
        for (int k = 0; k < CH_PER_W; ++k) {
            const int chunk = k * WAVES + wave;
            gload16(gbase + chunk * 256 + lane * 4, (char*)&buf[0][0] + chunk * 1024);
        }
    }
    __syncthreads();   // tree staged + tile0 DMA landed

    const float thr_root  = sthr[0];
    const int   feat_root = sfeat[0];

    int  node_prev = 0;
    long outPrev   = 0;

    for (int t = 0; t < TILES; ++t) {
        // ---- epilogue of tile t-1 (oldest VMEM this iter: its leaf-load
        //      consumption never waits on the DMA issued below) ----
        if (t > 0) {
#pragma unroll
            for (int j = 0; j < 2; ++j) {
                const int fid   = j * BLOCK + tid;   // 0..511 = 32 rows x 16 chunks
                const int r     = fid >> 4;
                const int chunk = fid & 15;
                const int leaf  = __shfl(node_prev, r, 64);
                const f32x4 v   = *(const f32x4*)(leaf_logits + (size_t)leaf * N_ACT + chunk * 4);
                __builtin_nontemporal_store(v, (f32x4*)(out + (outPrev + r) * N_ACT + chunk * 4));
            }
        }

        // ---- issue DMA for tile t+1 (youngest VMEM; flies during traversal) ----
        if (t + 1 < TILES) {
            const float* gbase = obs + (rowBase + (long)(t + 1) * TILE_ROWS) * N_FEAT;
            char* lbase = (char*)&buf[(t + 1) & 1][0];
#pragma unroll
            for (int k = 0; k < CH_PER_W; ++k) {
                const int chunk = k * WAVES + wave;
                gload16(gbase + chunk * 256 + lane * 4, lbase + chunk * 1024);
            }
        }
        __builtin_amdgcn_sched_barrier(0);   // keep DMA issue above traversal

        // ---- traversal of tile t: row = lane&31, child-prefetch form.
        //      Per step the obs lookup (feat from reg) and the children's
        //      thr/feat reads (from node) are INDEPENDENT -> 1 LDS round/step.
        const float* myrow = &buf[t & 1][(lane & 31) * N_FEAT];
        int   node = 0;
        float tcur = thr_root;
        int   fcur = feat_root;
#pragma unroll
        for (int d = 0; d < DEPTH - 1; ++d) {
            const float x   = myrow[fcur];
            const int   c   = 2 * node + 1;
            const float tl  = sthr[c];
            const float trr = sthr[c + 1];
            const int   fl  = sfeat[c];
            const int   fr  = sfeat[c + 1];
            const bool  L   = (x <= tcur);          // reference NaN semantics
            node = L ? c : (c + 1);
            tcur = L ? tl : trr;
            fcur = L ? fl : fr;
        }
        {   // last step peeled: children are leaves (no LDS entry; no reads)
            const float x = myrow[fcur];
            node = 2 * node + ((x <= tcur) ? 1 : 2);
        }
        node_prev = node;                    // leaf id in [16383, 32766]
        outPrev   = rowBase + (long)t * TILE_ROWS;

        // ---- drain DMA(t+1) (in-order vmcnt: older stores retire first),
        //      then raw barrier: all waves done reading buf[t&1] ----
        __builtin_amdgcn_sched_barrier(0);
        asm volatile("s_waitcnt vmcnt(0)" ::: "memory");
        __builtin_amdgcn_s_barrier();
        __builtin_amdgcn_sched_barrier(0);
    }

    // ---- final epilogue (tile TILES-1) ----
#pragma unroll
    for (int j = 0; j < 2; ++j) {
        const int fid   = j * BLOCK + tid;
        const int r     = fid >> 4;
        const int chunk = fid & 15;
        const int leaf  = __shfl(node_prev, r, 64);
        const f32x4 v   = *(const f32x4*)(leaf_logits + (size_t)leaf * N_ACT + chunk * 4);
        __builtin_nontemporal_store(v, (f32x4*)(out + (outPrev + r) * N_ACT + chunk * 4));
    }
}

extern "C" void kernel_launch(void* const* d_in, const int* in_sizes, int n_in,
                              void* d_out, int out_size, void* d_ws, size_t ws_size,
                              hipStream_t stream) {
    const float* obs         = (const float*)d_in[0];
    const int*   features    = (const int*)  d_in[1];
    const float* thresholds  = (const float*)d_in[2];
    // d_in[3]/d_in[4] (children) unused: tree is complete by construction.
    const float* leaf_logits = (const float*)d_in[5];
    float*       out         = (float*)d_out;

    tree_policy_kernel<<<dim3(GRID), dim3(BLOCK), 0, stream>>>(
        obs, features, thresholds, leaf_logits, out);
}

// Round 7
// 67.245 us; speedup vs baseline: 1.1881x; 1.1881x over previous
//
#include <hip/hip_runtime.h>

// DecisionTreePolicy — complete binary tree, depth 15 (32767 nodes).
// Internal 0..16382 (children 2i+1/2i+2), leaves 16383..32766 -> exactly 14
// steps from root; out[b] = leaf_logits[leaf(b)].
//
// History: R1/R2 scattered gathers -> 470MB HBM, 84us. R4 (best, 68.5us):
// obs streamed via LDS 64KB tiles, tree in LDS, reg-staged depth-1 prefetch.
// R5 (78us): 16-wave redundancy -> LDS-inst scaling. R6 (80us): vmcnt(0)
// drain per tile -> T4 anti-pattern.
// R7: R4 + counted-vmcnt DEPTH-2 pipeline. 32KB half-tiles in two named
// register groups (pfA even halves, pfB odd); write group h to LDS, re-issue
// it for h+2 -> 64KB always in flight; waits are vmcnt(12), never 0; stores
// never drained in-loop. One raw s_barrier per half-tile.

#define N_INTERN  16383
#define N_FEAT    256
#define N_ACT     64
#define BATCH     262144
#define BLOCK     256
#define GRID      256
#define ROWS_PB   (BATCH / GRID)      // 1024 rows per block
#define HROWS     32                  // rows per half-tile (32 KB)
#define HALVES    (ROWS_PB / HROWS)   // 32
#define DEPTH     14
#define PFN       8                   // f32x4 per thread per half: 32KB/256thr/16B
#define HSLOTS    (HROWS * N_FEAT / 4)  // 2048 f32x4 per half-tile

typedef float f32x4 __attribute__((ext_vector_type(4)));

__global__ __launch_bounds__(BLOCK, 1) void tree_policy_kernel(
    const float* __restrict__ obs,          // [BATCH][N_FEAT]
    const int*   __restrict__ features,     // [N_NODES]
    const float* __restrict__ thresholds,   // [N_NODES]
    const float* __restrict__ leaf_logits,  // [N_NODES][N_ACT]
    float*       __restrict__ out)          // [BATCH][N_ACT]
{
    __shared__ float         sthr [N_INTERN];                 // 64 KB
    __shared__ unsigned char sfeat[N_INTERN];                 // 16 KB
    __shared__ __align__(16) float buf[2][HROWS * N_FEAT];    // 2 x 32 KB  -> 143.6 KB total

    const int tid  = threadIdx.x;
    const int lane = tid & 63;
    const long rowBase = (long)blockIdx.x * ROWS_PB;

    // ---- tree -> LDS first (so tree loads are OLDER than all pf loads) ----
    for (int i = tid; i < N_INTERN; i += BLOCK) {
        sthr[i]  = thresholds[i];
        sfeat[i] = (unsigned char)features[i];
    }

    const f32x4* gsrc = (const f32x4*)(obs + rowBase * N_FEAT);

    // ---- prologue: fill the depth-2 pipe (halves 0 and 1) ----
    f32x4 pfA[PFN], pfB[PFN];
#pragma unroll
    for (int k = 0; k < PFN; ++k)
        pfA[k] = __builtin_nontemporal_load(&gsrc[0 * HSLOTS + k * BLOCK + tid]);
#pragma unroll
    for (int k = 0; k < PFN; ++k)
        pfB[k] = __builtin_nontemporal_load(&gsrc[1 * HSLOTS + k * BLOCK + tid]);

    asm volatile("s_waitcnt lgkmcnt(0)" ::: "memory");   // tree ds_writes done
    __builtin_amdgcn_s_barrier();                        // tree visible to all waves

    const float thr_root  = sthr[0];
    const int   feat_root = sfeat[0];

    auto half_body = [&](int h, f32x4 (&pf)[PFN]) {
        const int b = h & 1;
        // (1) counted wait: group h's 8 loads retired; younger ops (group h+1's
        // 8 loads + previous epilogue's 2 gathers + 2 stores) stay in flight.
        if (h == 0 || h == HALVES - 1)
            asm volatile("s_waitcnt vmcnt(8)" ::: "memory");
        else
            asm volatile("s_waitcnt vmcnt(12)" ::: "memory");
        __builtin_amdgcn_sched_barrier(0);
        // (2) regs -> LDS
#pragma unroll
        for (int k = 0; k < PFN; ++k)
            *(f32x4*)&buf[b][(k * BLOCK + tid) * 4] = pf[k];
        // (3) immediately re-issue this register group for half h+2
        if (h + 2 < HALVES) {
#pragma unroll
            for (int k = 0; k < PFN; ++k)
                pf[k] = __builtin_nontemporal_load(&gsrc[(h + 2) * HSLOTS + k * BLOCK + tid]);
        }
        asm volatile("s_waitcnt lgkmcnt(0)" ::: "memory");  // my ds_writes committed
        __builtin_amdgcn_s_barrier();                        // buf[b] visible; one barrier/half
        __builtin_amdgcn_sched_barrier(0);

        // (4) traversal: row = lane&31 (2x wave-internal redundancy = LDS
        // broadcast, free). Child-prefetch form: obs lookup (fcur in reg) and
        // children's thr/feat reads are independent -> 1 LDS round-trip/step.
        const float* myrow = &buf[b][(lane & 31) * N_FEAT];
        int   node = 0;
        float tcur = thr_root;
        int   fcur = feat_root;
#pragma unroll
        for (int d = 0; d < DEPTH - 1; ++d) {
            const float x   = myrow[fcur];
            const int   c   = 2 * node + 1;
            const float tl  = sthr[c];
            const float trr = sthr[c + 1];
            const int   fl  = sfeat[c];
            const int   fr  = sfeat[c + 1];
            const bool  L   = (x <= tcur);          // reference NaN semantics
            node = L ? c : c + 1;
            tcur = L ? tl : trr;
            fcur = L ? fl : fr;
        }
        {   // last step peeled: children are leaves (no LDS entries)
            const float x = myrow[fcur];
            node = 2 * node + ((x <= tcur) ? 1 : 2);
        }
        // node = leaf id in [16383, 32766]

        // (5) epilogue: 32 rows x 64 floats = 512 f32x4, 2 per thread;
        // leaf rows gathered from L2/L3, output as nontemporal streams.
        const long outRow0 = rowBase + (long)h * HROWS;
#pragma unroll
        for (int j = 0; j < 2; ++j) {
            const int fid   = j * BLOCK + tid;   // 0..511
            const int r     = fid >> 4;          // row in half [0,32)
            const int chunk = fid & 15;          // f32x4 chunk within 64-float row
            const int leaf  = __shfl(node, r, 64);
            const f32x4 v   = *(const f32x4*)(leaf_logits + (size_t)leaf * N_ACT + chunk * 4);
            __builtin_nontemporal_store(v, (f32x4*)(out + (outRow0 + r) * N_ACT + chunk * 4));
        }
    };

    for (int h = 0; h < HALVES; h += 2) {
        half_body(h,     pfA);
        half_body(h + 1, pfB);
    }
}

extern "C" void kernel_launch(void* const* d_in, const int* in_sizes, int n_in,
                              void* d_out, int out_size, void* d_ws, size_t ws_size,
                              hipStream_t stream) {
    const float* obs         = (const float*)d_in[0];
    const int*   features    = (const int*)  d_in[1];
    const float* thresholds  = (const float*)d_in[2];
    // d_in[3]/d_in[4] (children) unused: tree is complete by construction.
    const float* leaf_logits = (const float*)d_in[5];
    float*       out         = (float*)d_out;

    tree_policy_kernel<<<dim3(GRID), dim3(BLOCK), 0, stream>>>(
        obs, features, thresholds, leaf_logits, out);
}